// Round 6
// baseline (285.901 us; speedup 1.0000x reference)
//
#include <hip/hip_runtime.h>
#include <cstdint>
#include <cmath>

#define S_LEN 4096
#define B_N   16
#define C_N   512
#define CM1   511
#define T_M   512

// ws layout (float-unit offsets)
#define OFF_LW    65536     // fp32 [B][S]
#define OFF_RW    131072    // fp32 [B][S]
#define OFF_DEST  196640    // int  [B][S+1] = 16*4097
#define OFF_FEATS 262208    // bf16 [8192][512]  (occupies 2097152 float slots)
#define OFF_WB    2359360   // bf16 [512][512]   (occupies 131072 float slots)

__device__ __forceinline__ unsigned short f2bf(float f) {   // round-to-nearest-even
    unsigned u = __float_as_uint(f);
    return (unsigned short)((u + 0x7fffu + ((u >> 16) & 1u)) >> 16);
}

// ---------------- K_front: sigmoid + alpha_sum + scale + parallel scan ----------------
__global__ __launch_bounds__(256) void k_front(const float* __restrict__ x,
                                               const uint8_t* __restrict__ mask,
                                               const int* __restrict__ tl,
                                               float* __restrict__ ws,
                                               float* __restrict__ out_asum) {
    int b = blockIdx.x;
    int t = threadIdx.x;
    int lane = t & 63, wid = t >> 6;
    int s0 = t * 16;

    __shared__ float ssum[4];
    __shared__ float wsum[4];
    __shared__ float linc[256];

    float a[16];
    #pragma unroll
    for (int i = 0; i < 16; ++i) {
        int s = s0 + i;
        float v = x[((size_t)s * B_N + b) * C_N + CM1];
        if (mask[(size_t)b * S_LEN + s]) v = -10000.0f;
        a[i] = 1.0f / (1.0f + expf(-v));
    }

    float ls = 0.0f;
    #pragma unroll
    for (int i = 0; i < 16; ++i) ls += a[i];
    #pragma unroll
    for (int off = 32; off >= 1; off >>= 1) ls += __shfl_xor(ls, off, 64);
    if (lane == 0) ssum[wid] = ls;
    __syncthreads();
    float tot = (ssum[0] + ssum[1]) + (ssum[2] + ssum[3]);
    if (t == 0) out_asum[b] = tot;

    float tlf = (float)tl[b];
    #pragma unroll
    for (int i = 0; i < 16; ++i) a[i] = (a[i] * tlf) / tot;

    float p[16];
    float run = 0.0f;
    #pragma unroll
    for (int i = 0; i < 16; ++i) { run += a[i]; p[i] = run; }

    float sc = run;
    #pragma unroll
    for (int off = 1; off < 64; off <<= 1) {
        float v = __shfl_up(sc, off, 64);
        if (lane >= off) sc += v;
    }
    if (lane == 63) wsum[wid] = sc;
    __syncthreads();
    float woff = 0.0f;
    for (int w = 0; w < wid; ++w) woff += wsum[w];
    float excl = woff + (sc - run);

    linc[t] = excl + p[15];
    __syncthreads();
    float dsrc = (t == 0) ? 0.0f : linc[t - 1];
    int dprev = (int)floorf(dsrc + 1e-4f);

    float* lw   = ws + OFF_LW + (size_t)b * S_LEN;
    float* rw   = ws + OFF_RW + (size_t)b * S_LEN;
    int*   dest = (int*)(ws + OFF_DEST) + b * 4097;
    if (t == 0) dest[0] = 0;

    float lwv[16], rwv[16];
    int dnv[16];
    #pragma unroll
    for (int i = 0; i < 16; ++i) {
        float c  = excl + p[i];
        int   dn = (int)floorf(c + 1e-4f);
        int fire = dn - dprev;
        float rv = (fire > 0) ? (c - (float)dn) : a[i];
        float ex = (fire > 1) ? (float)(fire - 1) : 0.0f;
        lwv[i] = (a[i] - rv) - ex;
        rwv[i] = rv;
        dnv[i] = dn;
        dprev = dn;
    }
    #pragma unroll
    for (int q = 0; q < 4; ++q) {
        *(float4*)&lw[s0 + q * 4] = make_float4(lwv[q*4+0], lwv[q*4+1], lwv[q*4+2], lwv[q*4+3]);
        *(float4*)&rw[s0 + q * 4] = make_float4(rwv[q*4+0], rwv[q*4+1], rwv[q*4+2], rwv[q*4+3]);
    }
    #pragma unroll
    for (int i = 0; i < 16; ++i) dest[s0 + i + 1] = dnv[i];
}

// ---------------- K_wconv: W [512][511] fp32 -> Wb [512][512] bf16 (k padded) --------
__global__ __launch_bounds__(256) void k_wconv(const float* __restrict__ W,
                                               float* __restrict__ ws) {
    int g = blockIdx.x * 256 + threadIdx.x;   // 0..65535
    int n  = g >> 7;
    int kq = (g & 127) * 4;
    float v[4];
    #pragma unroll
    for (int j = 0; j < 4; ++j) {
        int k = kq + j;
        v[j] = (k < CM1) ? W[(size_t)n * CM1 + k] : 0.0f;
    }
    ushort4 o;
    o.x = f2bf(v[0]); o.y = f2bf(v[1]); o.z = f2bf(v[2]); o.w = f2bf(v[3]);
    unsigned short* Wb = (unsigned short*)(ws + OFF_WB);
    *(ushort4*)&Wb[(size_t)n * 512 + kq] = o;
}

// ---------------- K_gather v4: s-major, TT=4, dual strand, 4-deep load pipeline ------
// Grid (128,16). Block: 4 t-rows, contiguous s-range. 128 lanes = one 2KB x-row
// (float4/lane); strands take even/odd s. Hot loop keeps 4 row-loads in flight per
// wave (prefetch distance 8 rows, clamped index, rotating register slots).
#define TT 4
#define CHK 128
#define PF 4
__global__ __launch_bounds__(256) void k_gather(const float* __restrict__ x,
                                                float* __restrict__ ws) {
    int b   = blockIdx.y;
    int t0  = blockIdx.x * TT;
    int tid = threadIdx.x;
    int l   = tid & 127;
    int sub = tid >> 7;
    const int*   db = (const int*)(ws + OFF_DEST) + b * 4097;
    const float* lw = ws + OFF_LW + (size_t)b * S_LEN;
    const float* rw = ws + OFF_RW + (size_t)b * S_LEN;

    // s_lo: first s with db[s+1] >= t0
    int lo = 1, hi = 4097;
    while (lo < hi) {
        int mid = (lo + hi) >> 1;
        int v = (mid <= 4096) ? db[mid] : 0x7fffffff;
        if (v >= t0) hi = mid; else lo = mid + 1;
    }
    int s_lo = lo - 1;
    // s_hi: last s with db[s] <= t1
    int t1 = t0 + TT - 1;
    lo = 0; hi = 4097;
    while (lo < hi) {
        int mid = (lo + hi) >> 1;
        int v = (mid <= 4096) ? db[mid] : 0x7fffffff;
        if (v > t1) hi = mid; else lo = mid + 1;
    }
    int s_hi = lo - 1; if (s_hi > 4095) s_hi = 4095;

    __shared__ float  swt[CHK * TT];      // 2 KB weights per chunk
    __shared__ float4 cls[TT][128];       // 8 KB strand-combine buffer

    float4 acc[TT];
    #pragma unroll
    for (int k = 0; k < TT; ++k) acc[k] = make_float4(0.0f, 0.0f, 0.0f, 0.0f);

    const float4* x4 = (const float4*)x;
    for (int scb = s_lo; scb <= s_hi; scb += CHK) {
        int nch = s_hi - scb + 1; if (nch > CHK) nch = CHK;
        __syncthreads();
        for (int e = tid; e < nch * TT; e += 256) {
            int j = e >> 2, k = e & 3;
            int s = scb + j;
            int ds = db[s], dn = db[s + 1];
            int t = t0 + k;
            float w = (t > ds && t < dn) ? 1.0f : 0.0f;
            if (t == ds) w += lw[s];
            if (t == dn) w += rw[s];
            swt[e] = w;
        }
        __syncthreads();

        // strand pipeline: this strand's rows are j = sub, sub+2, ... (< nch)
        int nIt = (nch - sub + 1) >> 1;               // iterations for this strand
        int jmax = nch - 1;
        float4 xv[PF];
        #pragma unroll
        for (int p = 0; p < PF; ++p) {
            int jj = sub + 2 * p; if (jj > jmax) jj = jmax;
            xv[p] = x4[((size_t)(scb + jj) * B_N + b) * 128 + l];
        }
        #pragma unroll 4
        for (int it = 0; it < nIt; ++it) {
            int j = sub + 2 * it;
            float4 cur = xv[it & (PF - 1)];
            int jn = j + 2 * PF; if (jn > jmax) jn = jmax;
            xv[it & (PF - 1)] = x4[((size_t)(scb + jn) * B_N + b) * 128 + l];
            float4 w = *(const float4*)&swt[j * 4];
            acc[0].x += w.x * cur.x; acc[0].y += w.x * cur.y; acc[0].z += w.x * cur.z; acc[0].w += w.x * cur.w;
            acc[1].x += w.y * cur.x; acc[1].y += w.y * cur.y; acc[1].z += w.y * cur.z; acc[1].w += w.y * cur.w;
            acc[2].x += w.z * cur.x; acc[2].y += w.z * cur.y; acc[2].z += w.z * cur.z; acc[2].w += w.z * cur.w;
            acc[3].x += w.w * cur.x; acc[3].y += w.w * cur.y; acc[3].z += w.w * cur.z; acc[3].w += w.w * cur.w;
        }
    }
    __syncthreads();
    if (sub == 1) {
        #pragma unroll
        for (int k = 0; k < TT; ++k) cls[k][l] = acc[k];
    }
    __syncthreads();
    if (sub == 0) {
        unsigned short* feats = (unsigned short*)(ws + OFF_FEATS);
        #pragma unroll
        for (int k = 0; k < TT; ++k) {
            float4 c1 = cls[k][l];
            float4 tv;
            tv.x = acc[k].x + c1.x; tv.y = acc[k].y + c1.y;
            tv.z = acc[k].z + c1.z; tv.w = acc[k].w + c1.w;
            if (l == 127) tv.w = 0.0f;     // channel 511 excluded (GEMM K zero-pad)
            ushort4 o;
            o.x = f2bf(tv.x); o.y = f2bf(tv.y); o.z = f2bf(tv.z); o.w = f2bf(tv.w);
            *(ushort4*)&feats[(size_t)(b * T_M + t0 + k) * 512 + l * 4] = o;
        }
    }
}

// ---------------- K_mfma: out[t,b,:] = feats @ Wb^T + b_out (bf16 MFMA) --------------
typedef __attribute__((ext_vector_type(8))) short bf16x8;
typedef __attribute__((ext_vector_type(4))) float f32x4;

__global__ __launch_bounds__(256) void k_mfma(const float* __restrict__ ws,
                                              const float* __restrict__ bo,
                                              float* __restrict__ out) {
    __shared__ uint4 Asl[8 * 128];   // 16 KB
    __shared__ uint4 Bsl[8 * 64];    // 8 KB
    const uint4* feats4 = (const uint4*)(ws + OFF_FEATS);
    const uint4* Wb4    = (const uint4*)(ws + OFF_WB);
    int tid  = threadIdx.x;
    int lane = tid & 63;
    int wv   = tid >> 6;
    int wm   = wv >> 1, wn = wv & 1;
    int quad = lane >> 4, r16 = lane & 15;
    int m0 = blockIdx.x * 128;
    int n0 = blockIdx.y * 64;

    f32x4 acc[4][2] = {};
    for (int k0 = 0; k0 < 512; k0 += 64) {
        __syncthreads();
        int kp = k0 >> 3;
        #pragma unroll
        for (int i = 0; i < 4; ++i) {
            int e = i * 256 + tid;
            int p = e & 7, m = e >> 3;
            Asl[p * 128 + m] = feats4[(size_t)(m0 + m) * 64 + kp + p];
        }
        #pragma unroll
        for (int i = 0; i < 2; ++i) {
            int e = i * 256 + tid;
            int p = e & 7, n = e >> 3;
            Bsl[p * 64 + n] = Wb4[(size_t)(n0 + n) * 64 + kp + p];
        }
        __syncthreads();
        #pragma unroll
        for (int kk = 0; kk < 2; ++kk) {
            bf16x8 af[4], bfr[2];
            #pragma unroll
            for (int mt = 0; mt < 4; ++mt)
                af[mt] = *(const bf16x8*)&Asl[(kk * 4 + quad) * 128 + wm * 64 + mt * 16 + r16];
            #pragma unroll
            for (int nt = 0; nt < 2; ++nt)
                bfr[nt] = *(const bf16x8*)&Bsl[(kk * 4 + quad) * 64 + wn * 32 + nt * 16 + r16];
            #pragma unroll
            for (int mt = 0; mt < 4; ++mt)
                #pragma unroll
                for (int nt = 0; nt < 2; ++nt)
                    acc[mt][nt] = __builtin_amdgcn_mfma_f32_16x16x32_bf16(af[mt], bfr[nt], acc[mt][nt], 0, 0, 0);
        }
    }
    #pragma unroll
    for (int nt = 0; nt < 2; ++nt) {
        int n = n0 + wn * 32 + nt * 16 + r16;
        float bias = bo[n];
        #pragma unroll
        for (int mt = 0; mt < 4; ++mt) {
            #pragma unroll
            for (int r = 0; r < 4; ++r) {
                int m = m0 + wm * 64 + mt * 16 + quad * 4 + r;
                int t = m & 511, b = m >> 9;
                out[((size_t)t * B_N + b) * C_N + n] = acc[mt][nt][r] + bias;
            }
        }
    }
}

extern "C" void kernel_launch(void* const* d_in, const int* in_sizes, int n_in,
                              void* d_out, int out_size, void* d_ws, size_t ws_size,
                              hipStream_t stream) {
    const float*   x    = (const float*)d_in[0];
    const uint8_t* mask = (const uint8_t*)d_in[1];
    const int*     tl   = (const int*)d_in[2];
    const float*   W    = (const float*)d_in[3];
    const float*   bo   = (const float*)d_in[4];
    float* out = (float*)d_out;
    float* ws  = (float*)d_ws;

    k_front <<<16, 256, 0, stream>>>(x, mask, tl, ws, out + (size_t)T_M * B_N * C_N);
    k_wconv <<<256, 256, 0, stream>>>(W, ws);
    k_gather<<<dim3(T_M / TT, B_N), 256, 0, stream>>>(x, ws);
    k_mfma  <<<dim3(64, 8), 256, 0, stream>>>(ws, bo, out);
}

// Round 7
// 241.977 us; speedup vs baseline: 1.1815x; 1.1815x over previous
//
#include <hip/hip_runtime.h>
#include <cstdint>
#include <cmath>

#define S_LEN 4096
#define B_N   16
#define C_N   512
#define CM1   511
#define T_M   512

// ws layout (float-unit offsets)
#define OFF_LW    65536     // fp32 [B][S]
#define OFF_RW    131072    // fp32 [B][S]
#define OFF_DEST  196640    // int  [B][S+1] = 16*4097
#define OFF_FEATS 262208    // bf16 [8192][512]  (occupies 2097152 float slots)
#define OFF_WB    2359360   // bf16 [512][512]   (occupies 131072 float slots)

__device__ __forceinline__ unsigned short f2bf(float f) {   // round-to-nearest-even
    unsigned u = __float_as_uint(f);
    return (unsigned short)((u + 0x7fffu + ((u >> 16) & 1u)) >> 16);
}

// ---------------- K_front: sigmoid + alpha_sum + scale + parallel scan ----------------
__global__ __launch_bounds__(256) void k_front(const float* __restrict__ x,
                                               const uint8_t* __restrict__ mask,
                                               const int* __restrict__ tl,
                                               float* __restrict__ ws,
                                               float* __restrict__ out_asum) {
    int b = blockIdx.x;
    int t = threadIdx.x;
    int lane = t & 63, wid = t >> 6;
    int s0 = t * 16;

    __shared__ float ssum[4];
    __shared__ float wsum[4];
    __shared__ float linc[256];

    float a[16];
    #pragma unroll
    for (int i = 0; i < 16; ++i) {
        int s = s0 + i;
        float v = x[((size_t)s * B_N + b) * C_N + CM1];
        if (mask[(size_t)b * S_LEN + s]) v = -10000.0f;
        a[i] = 1.0f / (1.0f + expf(-v));
    }

    float ls = 0.0f;
    #pragma unroll
    for (int i = 0; i < 16; ++i) ls += a[i];
    #pragma unroll
    for (int off = 32; off >= 1; off >>= 1) ls += __shfl_xor(ls, off, 64);
    if (lane == 0) ssum[wid] = ls;
    __syncthreads();
    float tot = (ssum[0] + ssum[1]) + (ssum[2] + ssum[3]);
    if (t == 0) out_asum[b] = tot;

    float tlf = (float)tl[b];
    #pragma unroll
    for (int i = 0; i < 16; ++i) a[i] = (a[i] * tlf) / tot;

    float p[16];
    float run = 0.0f;
    #pragma unroll
    for (int i = 0; i < 16; ++i) { run += a[i]; p[i] = run; }

    float sc = run;
    #pragma unroll
    for (int off = 1; off < 64; off <<= 1) {
        float v = __shfl_up(sc, off, 64);
        if (lane >= off) sc += v;
    }
    if (lane == 63) wsum[wid] = sc;
    __syncthreads();
    float woff = 0.0f;
    for (int w = 0; w < wid; ++w) woff += wsum[w];
    float excl = woff + (sc - run);

    linc[t] = excl + p[15];
    __syncthreads();
    float dsrc = (t == 0) ? 0.0f : linc[t - 1];
    int dprev = (int)floorf(dsrc + 1e-4f);

    float* lw   = ws + OFF_LW + (size_t)b * S_LEN;
    float* rw   = ws + OFF_RW + (size_t)b * S_LEN;
    int*   dest = (int*)(ws + OFF_DEST) + b * 4097;
    if (t == 0) dest[0] = 0;

    float lwv[16], rwv[16];
    int dnv[16];
    #pragma unroll
    for (int i = 0; i < 16; ++i) {
        float c  = excl + p[i];
        int   dn = (int)floorf(c + 1e-4f);
        int fire = dn - dprev;
        float rv = (fire > 0) ? (c - (float)dn) : a[i];
        float ex = (fire > 1) ? (float)(fire - 1) : 0.0f;
        lwv[i] = (a[i] - rv) - ex;
        rwv[i] = rv;
        dnv[i] = dn;
        dprev = dn;
    }
    #pragma unroll
    for (int q = 0; q < 4; ++q) {
        *(float4*)&lw[s0 + q * 4] = make_float4(lwv[q*4+0], lwv[q*4+1], lwv[q*4+2], lwv[q*4+3]);
        *(float4*)&rw[s0 + q * 4] = make_float4(rwv[q*4+0], rwv[q*4+1], rwv[q*4+2], rwv[q*4+3]);
    }
    #pragma unroll
    for (int i = 0; i < 16; ++i) dest[s0 + i + 1] = dnv[i];
}

// ---------------- K_wconv: W [512][511] fp32 -> Wb [512][512] bf16 (k padded) --------
__global__ __launch_bounds__(256) void k_wconv(const float* __restrict__ W,
                                               float* __restrict__ ws) {
    int g = blockIdx.x * 256 + threadIdx.x;   // 0..65535
    int n  = g >> 7;
    int kq = (g & 127) * 4;
    float v[4];
    #pragma unroll
    for (int j = 0; j < 4; ++j) {
        int k = kq + j;
        v[j] = (k < CM1) ? W[(size_t)n * CM1 + k] : 0.0f;
    }
    ushort4 o;
    o.x = f2bf(v[0]); o.y = f2bf(v[1]); o.z = f2bf(v[2]); o.w = f2bf(v[3]);
    unsigned short* Wb = (unsigned short*)(ws + OFF_WB);
    *(ushort4*)&Wb[(size_t)n * 512 + kq] = o;
}

// ---------------- K_gather v5: s-major, TT=4, dual strand, 4 named loads/iter --------
// Grid (128,16). Block: 4 t-rows, contiguous s-range (dest monotone). 128 lanes
// cover one 2KB x-row (float4/lane); strands take even/odd s. Each iteration issues
// FOUR independent individually-named row loads (no arrays -> no scratch spill),
// giving 4 KB in flight per wave. Tail: clamped row index + zero weight.
#define TT 4
#define CHK 128
__global__ __launch_bounds__(256) void k_gather(const float* __restrict__ x,
                                                float* __restrict__ ws) {
    int b   = blockIdx.y;
    int t0  = blockIdx.x * TT;
    int tid = threadIdx.x;
    int l   = tid & 127;
    int sub = tid >> 7;
    const int*   db = (const int*)(ws + OFF_DEST) + b * 4097;
    const float* lw = ws + OFF_LW + (size_t)b * S_LEN;
    const float* rw = ws + OFF_RW + (size_t)b * S_LEN;

    // s_lo: first s with db[s+1] >= t0
    int lo = 1, hi = 4097;
    while (lo < hi) {
        int mid = (lo + hi) >> 1;
        int v = (mid <= 4096) ? db[mid] : 0x7fffffff;
        if (v >= t0) hi = mid; else lo = mid + 1;
    }
    int s_lo = lo - 1;
    // s_hi: last s with db[s] <= t1
    int t1 = t0 + TT - 1;
    lo = 0; hi = 4097;
    while (lo < hi) {
        int mid = (lo + hi) >> 1;
        int v = (mid <= 4096) ? db[mid] : 0x7fffffff;
        if (v > t1) hi = mid; else lo = mid + 1;
    }
    int s_hi = lo - 1; if (s_hi > 4095) s_hi = 4095;

    __shared__ float  swt[CHK * TT];      // 2 KB weights per chunk
    __shared__ float4 cls[TT][128];       // 8 KB strand-combine buffer

    float4 acc[TT];
    #pragma unroll
    for (int k = 0; k < TT; ++k) acc[k] = make_float4(0.0f, 0.0f, 0.0f, 0.0f);

    const float4* x4 = (const float4*)x;
    const float4  wz = make_float4(0.0f, 0.0f, 0.0f, 0.0f);
    for (int scb = s_lo; scb <= s_hi; scb += CHK) {
        int nch = s_hi - scb + 1; if (nch > CHK) nch = CHK;
        __syncthreads();
        for (int e = tid; e < nch * TT; e += 256) {
            int j = e >> 2, k = e & 3;
            int s = scb + j;
            int ds = db[s], dn = db[s + 1];
            int t = t0 + k;
            float w = (t > ds && t < dn) ? 1.0f : 0.0f;
            if (t == ds) w += lw[s];
            if (t == dn) w += rw[s];
            swt[e] = w;
        }
        __syncthreads();

        int jmax = nch - 1;
        // strand rows: j = sub, sub+2, ...; process 4 per iteration (named regs).
        for (int j0 = sub; j0 < nch; j0 += 8) {
            int jA = j0;
            int jB = j0 + 2; int cB = (jB > jmax) ? jmax : jB;
            int jC = j0 + 4; int cC = (jC > jmax) ? jmax : jC;
            int jD = j0 + 6; int cD = (jD > jmax) ? jmax : jD;
            float4 a0 = x4[((size_t)(scb + jA) * B_N + b) * 128 + l];
            float4 a1 = x4[((size_t)(scb + cB) * B_N + b) * 128 + l];
            float4 a2 = x4[((size_t)(scb + cC) * B_N + b) * 128 + l];
            float4 a3 = x4[((size_t)(scb + cD) * B_N + b) * 128 + l];
            float4 w0 = *(const float4*)&swt[jA * 4];
            float4 w1 = (jB <= jmax) ? *(const float4*)&swt[jB * 4] : wz;
            float4 w2 = (jC <= jmax) ? *(const float4*)&swt[jC * 4] : wz;
            float4 w3 = (jD <= jmax) ? *(const float4*)&swt[jD * 4] : wz;
            acc[0].x += w0.x * a0.x; acc[0].y += w0.x * a0.y; acc[0].z += w0.x * a0.z; acc[0].w += w0.x * a0.w;
            acc[1].x += w0.y * a0.x; acc[1].y += w0.y * a0.y; acc[1].z += w0.y * a0.z; acc[1].w += w0.y * a0.w;
            acc[2].x += w0.z * a0.x; acc[2].y += w0.z * a0.y; acc[2].z += w0.z * a0.z; acc[2].w += w0.z * a0.w;
            acc[3].x += w0.w * a0.x; acc[3].y += w0.w * a0.y; acc[3].z += w0.w * a0.z; acc[3].w += w0.w * a0.w;
            acc[0].x += w1.x * a1.x; acc[0].y += w1.x * a1.y; acc[0].z += w1.x * a1.z; acc[0].w += w1.x * a1.w;
            acc[1].x += w1.y * a1.x; acc[1].y += w1.y * a1.y; acc[1].z += w1.y * a1.z; acc[1].w += w1.y * a1.w;
            acc[2].x += w1.z * a1.x; acc[2].y += w1.z * a1.y; acc[2].z += w1.z * a1.z; acc[2].w += w1.z * a1.w;
            acc[3].x += w1.w * a1.x; acc[3].y += w1.w * a1.y; acc[3].z += w1.w * a1.z; acc[3].w += w1.w * a1.w;
            acc[0].x += w2.x * a2.x; acc[0].y += w2.x * a2.y; acc[0].z += w2.x * a2.z; acc[0].w += w2.x * a2.w;
            acc[1].x += w2.y * a2.x; acc[1].y += w2.y * a2.y; acc[1].z += w2.y * a2.z; acc[1].w += w2.y * a2.w;
            acc[2].x += w2.z * a2.x; acc[2].y += w2.z * a2.y; acc[2].z += w2.z * a2.z; acc[2].w += w2.z * a2.w;
            acc[3].x += w2.w * a2.x; acc[3].y += w2.w * a2.y; acc[3].z += w2.w * a2.z; acc[3].w += w2.w * a2.w;
            acc[0].x += w3.x * a3.x; acc[0].y += w3.x * a3.y; acc[0].z += w3.x * a3.z; acc[0].w += w3.x * a3.w;
            acc[1].x += w3.y * a3.x; acc[1].y += w3.y * a3.y; acc[1].z += w3.y * a3.z; acc[1].w += w3.y * a3.w;
            acc[2].x += w3.z * a3.x; acc[2].y += w3.z * a3.y; acc[2].z += w3.z * a3.z; acc[2].w += w3.z * a3.w;
            acc[3].x += w3.w * a3.x; acc[3].y += w3.w * a3.y; acc[3].z += w3.w * a3.z; acc[3].w += w3.w * a3.w;
        }
    }
    __syncthreads();
    if (sub == 1) {
        #pragma unroll
        for (int k = 0; k < TT; ++k) cls[k][l] = acc[k];
    }
    __syncthreads();
    if (sub == 0) {
        unsigned short* feats = (unsigned short*)(ws + OFF_FEATS);
        #pragma unroll
        for (int k = 0; k < TT; ++k) {
            float4 c1 = cls[k][l];
            float4 tv;
            tv.x = acc[k].x + c1.x; tv.y = acc[k].y + c1.y;
            tv.z = acc[k].z + c1.z; tv.w = acc[k].w + c1.w;
            if (l == 127) tv.w = 0.0f;     // channel 511 excluded (GEMM K zero-pad)
            ushort4 o;
            o.x = f2bf(tv.x); o.y = f2bf(tv.y); o.z = f2bf(tv.z); o.w = f2bf(tv.w);
            *(ushort4*)&feats[(size_t)(b * T_M + t0 + k) * 512 + l * 4] = o;
        }
    }
}

// ---------------- K_mfma: out[t,b,:] = feats @ Wb^T + b_out (bf16 MFMA) --------------
typedef __attribute__((ext_vector_type(8))) short bf16x8;
typedef __attribute__((ext_vector_type(4))) float f32x4;

__global__ __launch_bounds__(256) void k_mfma(const float* __restrict__ ws,
                                              const float* __restrict__ bo,
                                              float* __restrict__ out) {
    __shared__ uint4 Asl[8 * 128];   // 16 KB
    __shared__ uint4 Bsl[8 * 64];    // 8 KB
    const uint4* feats4 = (const uint4*)(ws + OFF_FEATS);
    const uint4* Wb4    = (const uint4*)(ws + OFF_WB);
    int tid  = threadIdx.x;
    int lane = tid & 63;
    int wv   = tid >> 6;
    int wm   = wv >> 1, wn = wv & 1;
    int quad = lane >> 4, r16 = lane & 15;
    int m0 = blockIdx.x * 128;
    int n0 = blockIdx.y * 64;

    f32x4 acc[4][2] = {};
    for (int k0 = 0; k0 < 512; k0 += 64) {
        __syncthreads();
        int kp = k0 >> 3;
        #pragma unroll
        for (int i = 0; i < 4; ++i) {
            int e = i * 256 + tid;
            int p = e & 7, m = e >> 3;
            Asl[p * 128 + m] = feats4[(size_t)(m0 + m) * 64 + kp + p];
        }
        #pragma unroll
        for (int i = 0; i < 2; ++i) {
            int e = i * 256 + tid;
            int p = e & 7, n = e >> 3;
            Bsl[p * 64 + n] = Wb4[(size_t)(n0 + n) * 64 + kp + p];
        }
        __syncthreads();
        #pragma unroll
        for (int kk = 0; kk < 2; ++kk) {
            bf16x8 af[4], bfr[2];
            #pragma unroll
            for (int mt = 0; mt < 4; ++mt)
                af[mt] = *(const bf16x8*)&Asl[(kk * 4 + quad) * 128 + wm * 64 + mt * 16 + r16];
            #pragma unroll
            for (int nt = 0; nt < 2; ++nt)
                bfr[nt] = *(const bf16x8*)&Bsl[(kk * 4 + quad) * 64 + wn * 32 + nt * 16 + r16];
            #pragma unroll
            for (int mt = 0; mt < 4; ++mt)
                #pragma unroll
                for (int nt = 0; nt < 2; ++nt)
                    acc[mt][nt] = __builtin_amdgcn_mfma_f32_16x16x32_bf16(af[mt], bfr[nt], acc[mt][nt], 0, 0, 0);
        }
    }
    #pragma unroll
    for (int nt = 0; nt < 2; ++nt) {
        int n = n0 + wn * 32 + nt * 16 + r16;
        float bias = bo[n];
        #pragma unroll
        for (int mt = 0; mt < 4; ++mt) {
            #pragma unroll
            for (int r = 0; r < 4; ++r) {
                int m = m0 + wm * 64 + mt * 16 + quad * 4 + r;
                int t = m & 511, b = m >> 9;
                out[((size_t)t * B_N + b) * C_N + n] = acc[mt][nt][r] + bias;
            }
        }
    }
}

extern "C" void kernel_launch(void* const* d_in, const int* in_sizes, int n_in,
                              void* d_out, int out_size, void* d_ws, size_t ws_size,
                              hipStream_t stream) {
    const float*   x    = (const float*)d_in[0];
    const uint8_t* mask = (const uint8_t*)d_in[1];
    const int*     tl   = (const int*)d_in[2];
    const float*   W    = (const float*)d_in[3];
    const float*   bo   = (const float*)d_in[4];
    float* out = (float*)d_out;
    float* ws  = (float*)d_ws;

    k_front <<<16, 256, 0, stream>>>(x, mask, tl, ws, out + (size_t)T_M * B_N * C_N);
    k_wconv <<<256, 256, 0, stream>>>(W, ws);
    k_gather<<<dim3(T_M / TT, B_N), 256, 0, stream>>>(x, ws);
    k_mfma  <<<dim3(64, 8), 256, 0, stream>>>(ws, bo, out);
}